// Round 12
// baseline (173.832 us; speedup 1.0000x reference)
//
#include <hip/hip_runtime.h>

typedef __bf16 bf16_t;
typedef __bf16 bf16x8 __attribute__((ext_vector_type(8)));
typedef __bf16 bf16x4 __attribute__((ext_vector_type(4)));
typedef float f32x4 __attribute__((ext_vector_type(4)));
typedef unsigned short u16x8 __attribute__((ext_vector_type(8)));

#define AS1C(p) ((const __attribute__((address_space(1))) void*)(p))
#define AS3(p) ((__attribute__((address_space(3))) void*)(p))
#define MM(a, b, c) __builtin_amdgcn_mfma_f32_16x16x32_bf16(a, b, c, 0, 0, 0)

__device__ __forceinline__ unsigned short f2b_rne(float f) {
  union { float f; unsigned u; } x; x.f = f;
  unsigned u = x.u;
  u += 0x7fffu + ((u >> 16) & 1u);
  return (unsigned short)(u >> 16);
}

__device__ __forceinline__ float fast_exp2(float x) {
  return __builtin_amdgcn_exp2f(x);
}

// ---------------- cast f32 -> bf16 (vectorized, 8 elts/thread) ----------------
__global__ __launch_bounds__(256) void cast_f32_bf16(const float* __restrict__ in,
                                                     unsigned short* __restrict__ out,
                                                     int n) {
  int i = (blockIdx.x * 256 + threadIdx.x) * 8;
  if (i >= n) return;
  const float4* p = reinterpret_cast<const float4*>(in + i);
  float4 a = p[0], b = p[1];
  u16x8 o;
  o[0] = f2b_rne(a.x); o[1] = f2b_rne(a.y); o[2] = f2b_rne(a.z); o[3] = f2b_rne(a.w);
  o[4] = f2b_rne(b.x); o[5] = f2b_rne(b.y); o[6] = f2b_rne(b.z); o[7] = f2b_rne(b.w);
  *reinterpret_cast<u16x8*>(out + i) = o;
}

// four 1024x1024 weight casts in one launch; out slots contiguous (2 MB apart)
__global__ __launch_bounds__(256) void cast_w4(const float* __restrict__ w0,
                                               const float* __restrict__ w1,
                                               const float* __restrict__ w2,
                                               const float* __restrict__ w3,
                                               unsigned short* __restrict__ out) {
  const float* in = (blockIdx.y == 0) ? w0 : (blockIdx.y == 1) ? w1
                  : (blockIdx.y == 2) ? w2 : w3;
  int i = (blockIdx.x * 256 + threadIdx.x) * 8;
  unsigned short* o = out + (size_t)blockIdx.y * (1024u * 1024u);
  const float4* p = reinterpret_cast<const float4*>(in + i);
  float4 a = p[0], b = p[1];
  u16x8 v;
  v[0] = f2b_rne(a.x); v[1] = f2b_rne(a.y); v[2] = f2b_rne(a.z); v[3] = f2b_rne(a.w);
  v[4] = f2b_rne(b.x); v[5] = f2b_rne(b.y); v[6] = f2b_rne(b.z); v[7] = f2b_rne(b.w);
  *reinterpret_cast<u16x8*>(o + i) = v;
}

// ============ 128 x (NJ*64) / BK=32 GEMM, 3-buffer counted-vmcnt pipeline ============
// C[M,N] = A[M,K] (row stride lda) * B[N,K]^T.  512 thr = 8 waves (2M x 4N).
// NJ=4: BN=256, per-wave 64x64 (acc 64 VGPR), LDS 72 KiB -> 2 blocks/CU (QKV: 768 blocks).
// NJ=2: BN=128, per-wave 64x32 (acc 32 VGPR), LDS 48 KiB -> 2+ blocks/CU (Wo: 512 blocks).
// Pipeline: tile T in buf T%3; stage(T+2) issues during T's compute; counted vmcnt at the
// end of T retires stage(T+1)'s loads while stage(T+2) stays in flight (never drains to 0).
// BK=32 rows (64 B) are naturally bank-balanced -> no swizzle needed.
template <int OUT_F32, int NJ>
__global__ __launch_bounds__(512, 4) void gemmk(const bf16_t* __restrict__ A,
                                                const bf16_t* __restrict__ Bm,
                                                void* __restrict__ C,
                                                int M, int N, int K, int lda,
                                                float scale, int qlim) {
  constexpr int BN = NJ * 64;
  constexpr int BUFE = (128 + BN) * 32;      // elems per LDS buffer
  constexpr int LPS = (NJ == 4) ? 3 : 2;     // global_load_lds per stage
  extern __shared__ bf16_t lds[];            // 3 x BUFE
  const int tid = threadIdx.x;
  const int w = tid >> 6, l = tid & 63;
  const int r = l & 15, kg = l >> 4;
  const int wm = (w >> 2) * 64;
  const int wn = (w & 3) * (NJ * 16);
  const int m0 = blockIdx.y * 128, n0 = blockIdx.x * BN;
  const int srow = w * 16 + (l >> 2);        // staging row 0..127
  const int scol = (l & 3) * 8;
  const bf16_t* aS = A + (size_t)(m0 + srow) * lda + scol;
  const bf16_t* bS = Bm + (size_t)(n0 + srow) * K + scol;

  f32x4 acc[4][NJ] = {};

  auto STAGE = [&](bf16_t* sb, int kt) {
    __builtin_amdgcn_global_load_lds(AS1C(aS + kt * 32), AS3(sb + w * 512), 16, 0, 0);
    __builtin_amdgcn_global_load_lds(AS1C(bS + kt * 32), AS3(sb + 4096 + w * 512), 16, 0, 0);
    if (NJ == 4)
      __builtin_amdgcn_global_load_lds(AS1C(bS + (size_t)128 * K + kt * 32),
                                       AS3(sb + 8192 + w * 512), 16, 0, 0);
  };

  bf16_t* cur = lds;
  bf16_t* nxt = lds + BUFE;
  bf16_t* stg = lds + 2 * BUFE;

  STAGE(cur, 0);
  STAGE(nxt, 1);
  if (NJ == 4) asm volatile("s_waitcnt vmcnt(3)" ::: "memory");
  else         asm volatile("s_waitcnt vmcnt(2)" ::: "memory");
  __builtin_amdgcn_s_barrier();

  const int NT = K >> 5;
  for (int t = 0; t < NT; ++t) {
    bf16x8 AF[4], BF[NJ];
#pragma unroll
    for (int il = 0; il < 4; ++il)
      AF[il] = *reinterpret_cast<const bf16x8*>(cur + (wm + il * 16 + r) * 32 + kg * 8);
#pragma unroll
    for (int jl = 0; jl < NJ; ++jl)
      BF[jl] = *reinterpret_cast<const bf16x8*>(cur + 4096 + (wn + jl * 16 + r) * 32 + kg * 8);
    const int kt = (t + 2 < NT) ? t + 2 : t;   // tail: benign re-stage into unused buf
    STAGE(stg, kt);
    if (NJ == 4) asm volatile("s_waitcnt lgkmcnt(2)" ::: "memory");  // AF + BF0,BF1 resident
    else         asm volatile("s_waitcnt lgkmcnt(1)" ::: "memory");  // AF + BF0 resident
    __builtin_amdgcn_sched_barrier(0);
    __builtin_amdgcn_s_setprio(1);
#pragma unroll
    for (int il = 0; il < 4; ++il)
#pragma unroll
      for (int jl = 0; jl < NJ / 2; ++jl)
        acc[il][jl] = MM(AF[il], BF[jl], acc[il][jl]);
    __builtin_amdgcn_s_setprio(0);
    asm volatile("s_waitcnt lgkmcnt(0)" ::: "memory");
    __builtin_amdgcn_sched_barrier(0);
    __builtin_amdgcn_s_setprio(1);
#pragma unroll
    for (int il = 0; il < 4; ++il)
#pragma unroll
      for (int jl = NJ / 2; jl < NJ; ++jl)
        acc[il][jl] = MM(AF[il], BF[jl], acc[il][jl]);
    __builtin_amdgcn_s_setprio(0);
    if (NJ == 4) asm volatile("s_waitcnt vmcnt(3)" ::: "memory");   // next tile landed
    else         asm volatile("s_waitcnt vmcnt(2)" ::: "memory");
    __builtin_amdgcn_s_barrier();
    bf16_t* tmp = cur; cur = nxt; nxt = stg; stg = tmp;
  }

  // epilogue: rows m0 + wm + il*16 + kg*4 + v; cols n0 + wn + jl*16 + r
#pragma unroll
  for (int il = 0; il < 4; ++il)
#pragma unroll
    for (int jl = 0; jl < NJ; ++jl) {
      const int row0 = m0 + wm + il * 16 + kg * 4;
      const int col = n0 + wn + jl * 16 + r;
      const float sc = (col < qlim) ? scale : 1.0f;
#pragma unroll
      for (int v = 0; v < 4; ++v) {
        float val = acc[il][jl][v] * sc;
        size_t idx = (size_t)(row0 + v) * N + col;
        if (OUT_F32) reinterpret_cast<float*>(C)[idx] = val;
        else reinterpret_cast<unsigned short*>(C)[idx] = f2b_rne(val);
      }
    }
}

// ---------------- V transpose: qkv V-columns [B*S][3072](+2048) -> VT [B*H][64][2048] ----------------
__global__ __launch_bounds__(256) void transpose_v(const bf16_t* __restrict__ qkv,
                                                   bf16_t* __restrict__ vt) {
  __shared__ bf16_t Vs[64 * 72];
  const int t = threadIdx.x;
  const int s0 = blockIdx.x * 64;
  const int bh = blockIdx.y;
  const int b = bh >> 4, h = bh & 15;
  const size_t in_base = ((size_t)b * 2048 + s0) * 3072 + 2048 + h * 64;
#pragma unroll
  for (int c = 0; c < 2; ++c) {
    int chunk = c * 256 + t;
    int ss = chunk >> 3, dd = (chunk & 7) * 8;
    bf16x8 v = *reinterpret_cast<const bf16x8*>(qkv + in_base + (size_t)ss * 3072 + dd);
    *reinterpret_cast<bf16x8*>(Vs + ss * 72 + dd) = v;
  }
  __syncthreads();
  const size_t out_base = (size_t)bh * 64 * 2048 + s0;
#pragma unroll
  for (int c = 0; c < 2; ++c) {
    int chunk = c * 256 + t;
    int dd = chunk >> 3, ss = (chunk & 7) * 8;
    bf16x8 o;
#pragma unroll
    for (int j = 0; j < 8; ++j) o[j] = Vs[(ss + j) * 72 + dd];
    *reinterpret_cast<bf16x8*>(vt + out_base + (size_t)dd * 2048 + ss) = o;
  }
}

// ---------------- causal flash attention: DUAL-CONTEXT shared-KV-stream (round-11) ----------
// PMAP balances static 2-blocks/CU assignment: cost(p) ~ 33-p; pairing y with 11-y makes
// every CU's (round1 + round2) cost = 59 (was 56..62 with linear mapping).
__global__ __launch_bounds__(512, 4) void flash_attn(const bf16_t* __restrict__ QKV,
                                                     const bf16_t* __restrict__ VT,
                                                     unsigned short* __restrict__ O,
                                                     int ostride) {
  __shared__ bf16_t Ks[2][64 * 72];
  __shared__ bf16_t Vts[2][64 * 72];
  __shared__ bf16_t Pl[8][2][16 * 68];
  const int tid = threadIdx.x;
  const int lane = tid & 63, wave = tid >> 6;
  const int r = lane & 15, kg = lane >> 4;
  const int bh = blockIdx.x;
  const int y = blockIdx.y;            // 0..7
  const int pair = (y < 4) ? y : 11 - y;  // {0,1,2,3,7,6,5,4}: CU cost sums equalized
  const int b = bh >> 4, h = bh & 15;
  const size_t qkv_row0 = (size_t)b * 2048 * 3072;
  const int qcol = h * 64, kcol = 1024 + h * 64;
  const size_t vt_base = (size_t)bh * 64 * 2048;
  const size_t o_row0 = (size_t)b * 2048 * ostride;
  const int ocol = h * 64;
  const int srr = tid >> 3, scc = (tid & 7) * 8;

  const int q0L = pair * 128, q0H = (15 - pair) * 128;
  const int qrowL = q0L + wave * 16 + r, qrowH = q0H + wave * 16 + r;
  const int tmaxL = (q0L + wave * 16 + 15) >> 6;
  const int tmaxH = (q0H + wave * 16 + 15) >> 6;
  const int NT = 32 - 2 * pair;

  const size_t qoffL = qkv_row0 + (size_t)qrowL * 3072 + qcol;
  const size_t qoffH = qkv_row0 + (size_t)qrowH * 3072 + qcol;
  bf16x8 qfL0 = *reinterpret_cast<const bf16x8*>(QKV + qoffL + kg * 8);
  bf16x8 qfL1 = *reinterpret_cast<const bf16x8*>(QKV + qoffL + 32 + kg * 8);
  bf16x8 qfH0 = *reinterpret_cast<const bf16x8*>(QKV + qoffH + kg * 8);
  bf16x8 qfH1 = *reinterpret_cast<const bf16x8*>(QKV + qoffH + 32 + kg * 8);

  f32x4 oaccL[4] = {}, oaccH[4] = {};
  float mL = -3e30f, lL = 0.f, mH = -3e30f, lH = 0.f;

  bf16x8 gk = *reinterpret_cast<const bf16x8*>(QKV + qkv_row0 + (size_t)srr * 3072 + kcol + scc);
  bf16x8 gv = *reinterpret_cast<const bf16x8*>(VT + vt_base + (size_t)srr * 2048 + scc);

  for (int t = 0; t < NT; ++t) {
    const int buf = t & 1;
    *reinterpret_cast<bf16x8*>(&Ks[buf][srr * 72 + scc]) = gk;
    *reinterpret_cast<bf16x8*>(&Vts[buf][srr * 72 + scc]) = gv;
    __syncthreads();
    if (t + 1 < NT) {
      const int kv1 = (t + 1) * 64;
      gk = *reinterpret_cast<const bf16x8*>(QKV + qkv_row0 + (size_t)(kv1 + srr) * 3072 + kcol + scc);
      gv = *reinterpret_cast<const bf16x8*>(VT + vt_base + (size_t)srr * 2048 + kv1 + scc);
    }
    if (t > tmaxH) continue;

    const int kv0 = t * 64;
    const bool doL = (t <= tmaxL);

    // --- QK for both contexts (independent streams share K fragments) ---
    float valsL[16], valsH[16];
    __builtin_amdgcn_s_setprio(1);
#pragma unroll
    for (int nt = 0; nt < 4; ++nt) {
      bf16x8 kf0 = *reinterpret_cast<const bf16x8*>(&Ks[buf][(nt * 16 + r) * 72 + kg * 8]);
      bf16x8 kf1 = *reinterpret_cast<const bf16x8*>(&Ks[buf][(nt * 16 + r) * 72 + 32 + kg * 8]);
      f32x4 sH = {};
      sH = MM(kf0, qfH0, sH);
      sH = MM(kf1, qfH1, sH);
#pragma unroll
      for (int v = 0; v < 4; ++v) valsH[nt * 4 + v] = sH[v];
      if (doL) {
        f32x4 sL = {};
        sL = MM(kf0, qfL0, sL);
        sL = MM(kf1, qfL1, sL);
#pragma unroll
        for (int v = 0; v < 4; ++v) valsL[nt * 4 + v] = sL[v];
      }
    }
    __builtin_amdgcn_s_setprio(0);

    // --- L: softmax + PV (overlaps H's QK completion / H's softmax below) ---
    if (doL) {
      if (t == tmaxL) {
#pragma unroll
        for (int nt = 0; nt < 4; ++nt)
#pragma unroll
          for (int v = 0; v < 4; ++v)
            if (kv0 + nt * 16 + kg * 4 + v > qrowL) valsL[nt * 4 + v] = -3e30f;
      }
      float a0 = fmaxf(fmaxf(valsL[0], valsL[1]), valsL[2]);
      float a1 = fmaxf(fmaxf(valsL[3], valsL[4]), valsL[5]);
      float a2 = fmaxf(fmaxf(valsL[6], valsL[7]), valsL[8]);
      float a3 = fmaxf(fmaxf(valsL[9], valsL[10]), valsL[11]);
      float a4 = fmaxf(fmaxf(valsL[12], valsL[13]), valsL[14]);
      float pmax = fmaxf(fmaxf(fmaxf(a0, a1), fmaxf(a2, a3)), fmaxf(a4, valsL[15]));
      if (!__all(pmax <= mL + 8.0f)) {
        pmax = fmaxf(pmax, __shfl_xor(pmax, 16));
        pmax = fmaxf(pmax, __shfl_xor(pmax, 32));
        const float m_new = fmaxf(mL, pmax);
        const float alpha = fast_exp2(mL - m_new);
        lL *= alpha;
        f32x4 al;
#pragma unroll
        for (int v = 0; v < 4; ++v) al[v] = __shfl(alpha, kg * 4 + v);
#pragma unroll
        for (int dt = 0; dt < 4; ++dt)
#pragma unroll
          for (int v = 0; v < 4; ++v) oaccL[dt][v] *= al[v];
        mL = m_new;
      }
#pragma unroll
      for (int ii = 0; ii < 16; ++ii) {
        float p = fast_exp2(valsL[ii] - mL);
        valsL[ii] = p;
        lL += p;
      }
#pragma unroll
      for (int nt = 0; nt < 4; ++nt) {
        bf16x4 pb;
#pragma unroll
        for (int v = 0; v < 4; ++v) pb[v] = (bf16_t)valsL[nt * 4 + v];
        *reinterpret_cast<bf16x4*>(&Pl[wave][0][r * 68 + nt * 16 + kg * 4]) = pb;
      }
      bf16x8 pa0 = *reinterpret_cast<const bf16x8*>(&Pl[wave][0][r * 68 + kg * 8]);
      bf16x8 pa1 = *reinterpret_cast<const bf16x8*>(&Pl[wave][0][r * 68 + 32 + kg * 8]);
#pragma unroll
      for (int dt = 0; dt < 4; ++dt) {
        bf16x8 vb0 = *reinterpret_cast<const bf16x8*>(&Vts[buf][(dt * 16 + r) * 72 + kg * 8]);
        bf16x8 vb1 = *reinterpret_cast<const bf16x8*>(&Vts[buf][(dt * 16 + r) * 72 + 32 + kg * 8]);
        oaccL[dt] = MM(pa0, vb0, oaccL[dt]);
        oaccL[dt] = MM(pa1, vb1, oaccL[dt]);
      }
    }

    // --- H: softmax + PV ---
    {
      if (t == tmaxH) {
#pragma unroll
        for (int nt = 0; nt < 4; ++nt)
#pragma unroll
          for (int v = 0; v < 4; ++v)
            if (kv0 + nt * 16 + kg * 4 + v > qrowH) valsH[nt * 4 + v] = -3e30f;
      }
      float a0 = fmaxf(fmaxf(valsH[0], valsH[1]), valsH[2]);
      float a1 = fmaxf(fmaxf(valsH[3], valsH[4]), valsH[5]);
      float a2 = fmaxf(fmaxf(valsH[6], valsH[7]), valsH[8]);
      float a3 = fmaxf(fmaxf(valsH[9], valsH[10]), valsH[11]);
      float a4 = fmaxf(fmaxf(valsH[12], valsH[13]), valsH[14]);
      float pmax = fmaxf(fmaxf(fmaxf(a0, a1), fmaxf(a2, a3)), fmaxf(a4, valsH[15]));
      if (!__all(pmax <= mH + 8.0f)) {
        pmax = fmaxf(pmax, __shfl_xor(pmax, 16));
        pmax = fmaxf(pmax, __shfl_xor(pmax, 32));
        const float m_new = fmaxf(mH, pmax);
        const float alpha = fast_exp2(mH - m_new);
        lH *= alpha;
        f32x4 al;
#pragma unroll
        for (int v = 0; v < 4; ++v) al[v] = __shfl(alpha, kg * 4 + v);
#pragma unroll
        for (int dt = 0; dt < 4; ++dt)
#pragma unroll
          for (int v = 0; v < 4; ++v) oaccH[dt][v] *= al[v];
        mH = m_new;
      }
#pragma unroll
      for (int ii = 0; ii < 16; ++ii) {
        float p = fast_exp2(valsH[ii] - mH);
        valsH[ii] = p;
        lH += p;
      }
#pragma unroll
      for (int nt = 0; nt < 4; ++nt) {
        bf16x4 pb;
#pragma unroll
        for (int v = 0; v < 4; ++v) pb[v] = (bf16_t)valsH[nt * 4 + v];
        *reinterpret_cast<bf16x4*>(&Pl[wave][1][r * 68 + nt * 16 + kg * 4]) = pb;
      }
      bf16x8 pa0 = *reinterpret_cast<const bf16x8*>(&Pl[wave][1][r * 68 + kg * 8]);
      bf16x8 pa1 = *reinterpret_cast<const bf16x8*>(&Pl[wave][1][r * 68 + 32 + kg * 8]);
      __builtin_amdgcn_s_setprio(1);
#pragma unroll
      for (int dt = 0; dt < 4; ++dt) {
        bf16x8 vb0 = *reinterpret_cast<const bf16x8*>(&Vts[buf][(dt * 16 + r) * 72 + kg * 8]);
        bf16x8 vb1 = *reinterpret_cast<const bf16x8*>(&Vts[buf][(dt * 16 + r) * 72 + 32 + kg * 8]);
        oaccH[dt] = MM(pa0, vb0, oaccH[dt]);
        oaccH[dt] = MM(pa1, vb1, oaccH[dt]);
      }
      __builtin_amdgcn_s_setprio(0);
    }
  }

  // --- epilogue: both contexts ---
  {
    float l_row = lL;
    l_row += __shfl_xor(l_row, 16);
    l_row += __shfl_xor(l_row, 32);
    const float linv = 1.0f / l_row;
    f32x4 il;
#pragma unroll
    for (int v = 0; v < 4; ++v) il[v] = __shfl(linv, kg * 4 + v);
    const size_t orow0 = o_row0 + (size_t)(q0L + wave * 16) * ostride + ocol;
#pragma unroll
    for (int dt = 0; dt < 4; ++dt) {
      const int d = dt * 16 + r;
#pragma unroll
      for (int v = 0; v < 4; ++v)
        O[orow0 + (size_t)(kg * 4 + v) * ostride + d] = f2b_rne(oaccL[dt][v] * il[v]);
    }
  }
  {
    float l_row = lH;
    l_row += __shfl_xor(l_row, 16);
    l_row += __shfl_xor(l_row, 32);
    const float linv = 1.0f / l_row;
    f32x4 il;
#pragma unroll
    for (int v = 0; v < 4; ++v) il[v] = __shfl(linv, kg * 4 + v);
    const size_t orow0 = o_row0 + (size_t)(q0H + wave * 16) * ostride + ocol;
#pragma unroll
    for (int dt = 0; dt < 4; ++dt) {
      const int d = dt * 16 + r;
#pragma unroll
      for (int v = 0; v < 4; ++v)
        O[orow0 + (size_t)(kg * 4 + v) * ostride + d] = f2b_rne(oaccH[dt][v] * il[v]);
    }
  }
}

// ---------------- launcher ----------------
extern "C" void kernel_launch(void* const* d_in, const int* in_sizes, int n_in,
                              void* d_out, int out_size, void* d_ws, size_t ws_size,
                              hipStream_t stream) {
  const float* x  = (const float*)d_in[0];
  const float* Wq = (const float*)d_in[1];
  const float* Wk = (const float*)d_in[2];
  const float* Wv = (const float*)d_in[3];
  const float* Wo = (const float*)d_in[4];

  char* ws = (char*)d_ws;
  bf16_t* xb  = (bf16_t*)(ws);
  bf16_t* wqb = (bf16_t*)(ws + (16u << 20));
  bf16_t* wob = (bf16_t*)(ws + (22u << 20));
  bf16_t* qkv = (bf16_t*)(ws + (24u << 20));
  bf16_t* vt  = (bf16_t*)(ws);

  hipFuncSetAttribute(reinterpret_cast<const void*>(&gemmk<0, 4>),
                      hipFuncAttributeMaxDynamicSharedMemorySize, 73728);
  hipFuncSetAttribute(reinterpret_cast<const void*>(&gemmk<1, 2>),
                      hipFuncAttributeMaxDynamicSharedMemorySize, 49152);

  const int NX = 4 * 2048 * 1024;
  cast_f32_bf16<<<NX / 2048, 256, 0, stream>>>(x, (unsigned short*)xb, NX);
  cast_w4<<<dim3(512, 4), 256, 0, stream>>>(Wq, Wk, Wv, Wo, (unsigned short*)wqb);

  // fused QKV projection; Q cols scaled by 1/sqrt(dk)*log2(e) (exp2-domain softmax)
  gemmk<0, 4><<<dim3(3072 / 256, 8192 / 128), 512, 73728, stream>>>(
      xb, wqb, qkv, 8192, 3072, 1024, 1024, 0.18033688011112042f, 1024);

  transpose_v<<<dim3(2048 / 64, 64), 256, 0, stream>>>(qkv, vt);

  flash_attn<<<dim3(64, 8), 512, 0, stream>>>(qkv, vt, (unsigned short*)qkv, 3072);

  // output projection: BN=128 -> 512 blocks = 2/CU (was 256 at 1/CU)
  gemmk<1, 2><<<dim3(1024 / 128, 8192 / 128), 512, 49152, stream>>>(
      qkv, wob, d_out, 8192, 1024, 1024, 3072, 1.0f, 0);
}

// Round 13
// 172.938 us; speedup vs baseline: 1.0052x; 1.0052x over previous
//
#include <hip/hip_runtime.h>

typedef __bf16 bf16_t;
typedef __bf16 bf16x8 __attribute__((ext_vector_type(8)));
typedef __bf16 bf16x4 __attribute__((ext_vector_type(4)));
typedef float f32x4 __attribute__((ext_vector_type(4)));
typedef unsigned short u16x8 __attribute__((ext_vector_type(8)));

#define AS1C(p) ((const __attribute__((address_space(1))) void*)(p))
#define AS3(p) ((__attribute__((address_space(3))) void*)(p))
#define MM(a, b, c) __builtin_amdgcn_mfma_f32_16x16x32_bf16(a, b, c, 0, 0, 0)

__device__ __forceinline__ unsigned short f2b_rne(float f) {
  union { float f; unsigned u; } x; x.f = f;
  unsigned u = x.u;
  u += 0x7fffu + ((u >> 16) & 1u);
  return (unsigned short)(u >> 16);
}

__device__ __forceinline__ float fast_exp2(float x) {
  return __builtin_amdgcn_exp2f(x);
}

// ---------------- all f32->bf16 casts in ONE launch ----------------
// blocks [0, 4096): x (8M elems); [4096, 4608): Wq; +512 each: Wk, Wv, Wo.
// weight outputs land contiguously at wout + widx*1M elems.
__global__ __launch_bounds__(256) void cast_all(const float* __restrict__ x,
                                                const float* __restrict__ w0,
                                                const float* __restrict__ w1,
                                                const float* __restrict__ w2,
                                                const float* __restrict__ w3,
                                                unsigned short* __restrict__ xout,
                                                unsigned short* __restrict__ wout) {
  int bid = blockIdx.x;
  const float* in;
  unsigned short* out;
  int base;
  if (bid < 4096) {
    in = x; out = xout; base = bid * 2048;
  } else {
    int widx = (bid - 4096) >> 9;
    in = (widx == 0) ? w0 : (widx == 1) ? w1 : (widx == 2) ? w2 : w3;
    out = wout + (size_t)widx * (1024u * 1024u);
    base = ((bid - 4096) & 511) * 2048;
  }
  int i = base + threadIdx.x * 8;
  const float4* p = reinterpret_cast<const float4*>(in + i);
  float4 a = p[0], b = p[1];
  u16x8 o;
  o[0] = f2b_rne(a.x); o[1] = f2b_rne(a.y); o[2] = f2b_rne(a.z); o[3] = f2b_rne(a.w);
  o[4] = f2b_rne(b.x); o[5] = f2b_rne(b.y); o[6] = f2b_rne(b.z); o[7] = f2b_rne(b.w);
  *reinterpret_cast<u16x8*>(out + i) = o;
}

// ============ 128 x (NJ*64) / BK=32 GEMM, 3-buffer counted-vmcnt pipeline ============
// (round-11 verified; NJ=4 -> BN=256 for QKV at 2 blocks/CU, NJ=2 -> BN=128 for Wo)
template <int OUT_F32, int NJ>
__global__ __launch_bounds__(512, 4) void gemmk(const bf16_t* __restrict__ A,
                                                const bf16_t* __restrict__ Bm,
                                                void* __restrict__ C,
                                                int M, int N, int K, int lda,
                                                float scale, int qlim) {
  constexpr int BN = NJ * 64;
  constexpr int BUFE = (128 + BN) * 32;
  extern __shared__ bf16_t lds[];
  const int tid = threadIdx.x;
  const int w = tid >> 6, l = tid & 63;
  const int r = l & 15, kg = l >> 4;
  const int wm = (w >> 2) * 64;
  const int wn = (w & 3) * (NJ * 16);
  const int m0 = blockIdx.y * 128, n0 = blockIdx.x * BN;
  const int srow = w * 16 + (l >> 2);
  const int scol = (l & 3) * 8;
  const bf16_t* aS = A + (size_t)(m0 + srow) * lda + scol;
  const bf16_t* bS = Bm + (size_t)(n0 + srow) * K + scol;

  f32x4 acc[4][NJ] = {};

  auto STAGE = [&](bf16_t* sb, int kt) {
    __builtin_amdgcn_global_load_lds(AS1C(aS + kt * 32), AS3(sb + w * 512), 16, 0, 0);
    __builtin_amdgcn_global_load_lds(AS1C(bS + kt * 32), AS3(sb + 4096 + w * 512), 16, 0, 0);
    if (NJ == 4)
      __builtin_amdgcn_global_load_lds(AS1C(bS + (size_t)128 * K + kt * 32),
                                       AS3(sb + 8192 + w * 512), 16, 0, 0);
  };

  bf16_t* cur = lds;
  bf16_t* nxt = lds + BUFE;
  bf16_t* stg = lds + 2 * BUFE;

  STAGE(cur, 0);
  STAGE(nxt, 1);
  if (NJ == 4) asm volatile("s_waitcnt vmcnt(3)" ::: "memory");
  else         asm volatile("s_waitcnt vmcnt(2)" ::: "memory");
  __builtin_amdgcn_s_barrier();

  const int NT = K >> 5;
  for (int t = 0; t < NT; ++t) {
    bf16x8 AF[4], BF[NJ];
#pragma unroll
    for (int il = 0; il < 4; ++il)
      AF[il] = *reinterpret_cast<const bf16x8*>(cur + (wm + il * 16 + r) * 32 + kg * 8);
#pragma unroll
    for (int jl = 0; jl < NJ; ++jl)
      BF[jl] = *reinterpret_cast<const bf16x8*>(cur + 4096 + (wn + jl * 16 + r) * 32 + kg * 8);
    const int kt = (t + 2 < NT) ? t + 2 : t;
    STAGE(stg, kt);
    if (NJ == 4) asm volatile("s_waitcnt lgkmcnt(2)" ::: "memory");
    else         asm volatile("s_waitcnt lgkmcnt(1)" ::: "memory");
    __builtin_amdgcn_sched_barrier(0);
    __builtin_amdgcn_s_setprio(1);
#pragma unroll
    for (int il = 0; il < 4; ++il)
#pragma unroll
      for (int jl = 0; jl < NJ / 2; ++jl)
        acc[il][jl] = MM(AF[il], BF[jl], acc[il][jl]);
    __builtin_amdgcn_s_setprio(0);
    asm volatile("s_waitcnt lgkmcnt(0)" ::: "memory");
    __builtin_amdgcn_sched_barrier(0);
    __builtin_amdgcn_s_setprio(1);
#pragma unroll
    for (int il = 0; il < 4; ++il)
#pragma unroll
      for (int jl = NJ / 2; jl < NJ; ++jl)
        acc[il][jl] = MM(AF[il], BF[jl], acc[il][jl]);
    __builtin_amdgcn_s_setprio(0);
    if (NJ == 4) asm volatile("s_waitcnt vmcnt(3)" ::: "memory");
    else         asm volatile("s_waitcnt vmcnt(2)" ::: "memory");
    __builtin_amdgcn_s_barrier();
    bf16_t* tmp = cur; cur = nxt; nxt = stg; stg = tmp;
  }

#pragma unroll
  for (int il = 0; il < 4; ++il)
#pragma unroll
    for (int jl = 0; jl < NJ; ++jl) {
      const int row0 = m0 + wm + il * 16 + kg * 4;
      const int col = n0 + wn + jl * 16 + r;
      const float sc = (col < qlim) ? scale : 1.0f;
#pragma unroll
      for (int v = 0; v < 4; ++v) {
        float val = acc[il][jl][v] * sc;
        size_t idx = (size_t)(row0 + v) * N + col;
        if (OUT_F32) reinterpret_cast<float*>(C)[idx] = val;
        else reinterpret_cast<unsigned short*>(C)[idx] = f2b_rne(val);
      }
    }
}

// ---------------- V transpose: qkv V-columns [B*S][3072](+2048) -> VT [B*H][64][2048] ----------------
__global__ __launch_bounds__(256) void transpose_v(const bf16_t* __restrict__ qkv,
                                                   bf16_t* __restrict__ vt) {
  __shared__ bf16_t Vs[64 * 72];
  const int t = threadIdx.x;
  const int s0 = blockIdx.x * 64;
  const int bh = blockIdx.y;
  const int b = bh >> 4, h = bh & 15;
  const size_t in_base = ((size_t)b * 2048 + s0) * 3072 + 2048 + h * 64;
#pragma unroll
  for (int c = 0; c < 2; ++c) {
    int chunk = c * 256 + t;
    int ss = chunk >> 3, dd = (chunk & 7) * 8;
    bf16x8 v = *reinterpret_cast<const bf16x8*>(qkv + in_base + (size_t)ss * 3072 + dd);
    *reinterpret_cast<bf16x8*>(Vs + ss * 72 + dd) = v;
  }
  __syncthreads();
  const size_t out_base = (size_t)bh * 64 * 2048 + s0;
#pragma unroll
  for (int c = 0; c < 2; ++c) {
    int chunk = c * 256 + t;
    int dd = chunk >> 3, ss = (chunk & 7) * 8;
    bf16x8 o;
#pragma unroll
    for (int j = 0; j < 8; ++j) o[j] = Vs[(ss + j) * 72 + dd];
    *reinterpret_cast<bf16x8*>(vt + out_base + (size_t)dd * 2048 + ss) = o;
  }
}

// ---------------- causal flash attention: dual-context, QK_L-first ordering ----------------
// Per tile: load 8 kf -> QK_L cluster -> QK_H cluster -> L-softmax (VALU overlaps QK_H's
// async MFMA execution) -> L-PV -> H-softmax (overlaps L-PV) -> H-PV.  QK_L issued FIRST
// so L-softmax's dependency resolves while QK_H still occupies the matrix pipe (in-order
// issue, async completion).  Rest as round 11/12.
__global__ __launch_bounds__(512, 4) void flash_attn(const bf16_t* __restrict__ QKV,
                                                     const bf16_t* __restrict__ VT,
                                                     unsigned short* __restrict__ O,
                                                     int ostride) {
  __shared__ bf16_t Ks[2][64 * 72];
  __shared__ bf16_t Vts[2][64 * 72];
  __shared__ bf16_t Pl[8][2][16 * 68];
  const int tid = threadIdx.x;
  const int lane = tid & 63, wave = tid >> 6;
  const int r = lane & 15, kg = lane >> 4;
  const int bh = blockIdx.x;
  const int y = blockIdx.y;
  const int pair = (y < 4) ? y : 11 - y;
  const int b = bh >> 4, h = bh & 15;
  const size_t qkv_row0 = (size_t)b * 2048 * 3072;
  const int qcol = h * 64, kcol = 1024 + h * 64;
  const size_t vt_base = (size_t)bh * 64 * 2048;
  const size_t o_row0 = (size_t)b * 2048 * ostride;
  const int ocol = h * 64;
  const int srr = tid >> 3, scc = (tid & 7) * 8;

  const int q0L = pair * 128, q0H = (15 - pair) * 128;
  const int qrowL = q0L + wave * 16 + r, qrowH = q0H + wave * 16 + r;
  const int tmaxL = (q0L + wave * 16 + 15) >> 6;
  const int tmaxH = (q0H + wave * 16 + 15) >> 6;
  const int NT = 32 - 2 * pair;

  const size_t qoffL = qkv_row0 + (size_t)qrowL * 3072 + qcol;
  const size_t qoffH = qkv_row0 + (size_t)qrowH * 3072 + qcol;
  bf16x8 qfL0 = *reinterpret_cast<const bf16x8*>(QKV + qoffL + kg * 8);
  bf16x8 qfL1 = *reinterpret_cast<const bf16x8*>(QKV + qoffL + 32 + kg * 8);
  bf16x8 qfH0 = *reinterpret_cast<const bf16x8*>(QKV + qoffH + kg * 8);
  bf16x8 qfH1 = *reinterpret_cast<const bf16x8*>(QKV + qoffH + 32 + kg * 8);

  f32x4 oaccL[4] = {}, oaccH[4] = {};
  float mL = -3e30f, lL = 0.f, mH = -3e30f, lH = 0.f;

  bf16x8 gk = *reinterpret_cast<const bf16x8*>(QKV + qkv_row0 + (size_t)srr * 3072 + kcol + scc);
  bf16x8 gv = *reinterpret_cast<const bf16x8*>(VT + vt_base + (size_t)srr * 2048 + scc);

  for (int t = 0; t < NT; ++t) {
    const int buf = t & 1;
    *reinterpret_cast<bf16x8*>(&Ks[buf][srr * 72 + scc]) = gk;
    *reinterpret_cast<bf16x8*>(&Vts[buf][srr * 72 + scc]) = gv;
    __syncthreads();
    if (t + 1 < NT) {
      const int kv1 = (t + 1) * 64;
      gk = *reinterpret_cast<const bf16x8*>(QKV + qkv_row0 + (size_t)(kv1 + srr) * 3072 + kcol + scc);
      gv = *reinterpret_cast<const bf16x8*>(VT + vt_base + (size_t)srr * 2048 + kv1 + scc);
    }
    if (t > tmaxH) continue;

    const int kv0 = t * 64;
    const bool doL = (t <= tmaxL);

    // --- K fragments once; QK_L cluster first, then QK_H ---
    bf16x8 kf[4][2];
#pragma unroll
    for (int nt = 0; nt < 4; ++nt) {
      kf[nt][0] = *reinterpret_cast<const bf16x8*>(&Ks[buf][(nt * 16 + r) * 72 + kg * 8]);
      kf[nt][1] = *reinterpret_cast<const bf16x8*>(&Ks[buf][(nt * 16 + r) * 72 + 32 + kg * 8]);
    }
    float valsL[16], valsH[16];
    __builtin_amdgcn_s_setprio(1);
    if (doL) {
#pragma unroll
      for (int nt = 0; nt < 4; ++nt) {
        f32x4 sL = {};
        sL = MM(kf[nt][0], qfL0, sL);
        sL = MM(kf[nt][1], qfL1, sL);
#pragma unroll
        for (int v = 0; v < 4; ++v) valsL[nt * 4 + v] = sL[v];
      }
    }
#pragma unroll
    for (int nt = 0; nt < 4; ++nt) {
      f32x4 sH = {};
      sH = MM(kf[nt][0], qfH0, sH);
      sH = MM(kf[nt][1], qfH1, sH);
#pragma unroll
      for (int v = 0; v < 4; ++v) valsH[nt * 4 + v] = sH[v];
    }
    __builtin_amdgcn_s_setprio(0);

    // --- L: softmax (overlaps QK_H async completion) + PV ---
    if (doL) {
      if (t == tmaxL) {
#pragma unroll
        for (int nt = 0; nt < 4; ++nt)
#pragma unroll
          for (int v = 0; v < 4; ++v)
            if (kv0 + nt * 16 + kg * 4 + v > qrowL) valsL[nt * 4 + v] = -3e30f;
      }
      float a0 = fmaxf(fmaxf(valsL[0], valsL[1]), valsL[2]);
      float a1 = fmaxf(fmaxf(valsL[3], valsL[4]), valsL[5]);
      float a2 = fmaxf(fmaxf(valsL[6], valsL[7]), valsL[8]);
      float a3 = fmaxf(fmaxf(valsL[9], valsL[10]), valsL[11]);
      float a4 = fmaxf(fmaxf(valsL[12], valsL[13]), valsL[14]);
      float pmax = fmaxf(fmaxf(fmaxf(a0, a1), fmaxf(a2, a3)), fmaxf(a4, valsL[15]));
      if (!__all(pmax <= mL + 8.0f)) {
        pmax = fmaxf(pmax, __shfl_xor(pmax, 16));
        pmax = fmaxf(pmax, __shfl_xor(pmax, 32));
        const float m_new = fmaxf(mL, pmax);
        const float alpha = fast_exp2(mL - m_new);
        lL *= alpha;
        f32x4 al;
#pragma unroll
        for (int v = 0; v < 4; ++v) al[v] = __shfl(alpha, kg * 4 + v);
#pragma unroll
        for (int dt = 0; dt < 4; ++dt)
#pragma unroll
          for (int v = 0; v < 4; ++v) oaccL[dt][v] *= al[v];
        mL = m_new;
      }
#pragma unroll
      for (int ii = 0; ii < 16; ++ii) {
        float p = fast_exp2(valsL[ii] - mL);
        valsL[ii] = p;
        lL += p;
      }
#pragma unroll
      for (int nt = 0; nt < 4; ++nt) {
        bf16x4 pb;
#pragma unroll
        for (int v = 0; v < 4; ++v) pb[v] = (bf16_t)valsL[nt * 4 + v];
        *reinterpret_cast<bf16x4*>(&Pl[wave][0][r * 68 + nt * 16 + kg * 4]) = pb;
      }
      bf16x8 pa0 = *reinterpret_cast<const bf16x8*>(&Pl[wave][0][r * 68 + kg * 8]);
      bf16x8 pa1 = *reinterpret_cast<const bf16x8*>(&Pl[wave][0][r * 68 + 32 + kg * 8]);
#pragma unroll
      for (int dt = 0; dt < 4; ++dt) {
        bf16x8 vb0 = *reinterpret_cast<const bf16x8*>(&Vts[buf][(dt * 16 + r) * 72 + kg * 8]);
        bf16x8 vb1 = *reinterpret_cast<const bf16x8*>(&Vts[buf][(dt * 16 + r) * 72 + 32 + kg * 8]);
        oaccL[dt] = MM(pa0, vb0, oaccL[dt]);
        oaccL[dt] = MM(pa1, vb1, oaccL[dt]);
      }
    }

    // --- H: softmax (overlaps L-PV) + PV ---
    {
      if (t == tmaxH) {
#pragma unroll
        for (int nt = 0; nt < 4; ++nt)
#pragma unroll
          for (int v = 0; v < 4; ++v)
            if (kv0 + nt * 16 + kg * 4 + v > qrowH) valsH[nt * 4 + v] = -3e30f;
      }
      float a0 = fmaxf(fmaxf(valsH[0], valsH[1]), valsH[2]);
      float a1 = fmaxf(fmaxf(valsH[3], valsH[4]), valsH[5]);
      float a2 = fmaxf(fmaxf(valsH[6], valsH[7]), valsH[8]);
      float a3 = fmaxf(fmaxf(valsH[9], valsH[10]), valsH[11]);
      float a4 = fmaxf(fmaxf(valsH[12], valsH[13]), valsH[14]);
      float pmax = fmaxf(fmaxf(fmaxf(a0, a1), fmaxf(a2, a3)), fmaxf(a4, valsH[15]));
      if (!__all(pmax <= mH + 8.0f)) {
        pmax = fmaxf(pmax, __shfl_xor(pmax, 16));
        pmax = fmaxf(pmax, __shfl_xor(pmax, 32));
        const float m_new = fmaxf(mH, pmax);
        const float alpha = fast_exp2(mH - m_new);
        lH *= alpha;
        f32x4 al;
#pragma unroll
        for (int v = 0; v < 4; ++v) al[v] = __shfl(alpha, kg * 4 + v);
#pragma unroll
        for (int dt = 0; dt < 4; ++dt)
#pragma unroll
          for (int v = 0; v < 4; ++v) oaccH[dt][v] *= al[v];
        mH = m_new;
      }
#pragma unroll
      for (int ii = 0; ii < 16; ++ii) {
        float p = fast_exp2(valsH[ii] - mH);
        valsH[ii] = p;
        lH += p;
      }
#pragma unroll
      for (int nt = 0; nt < 4; ++nt) {
        bf16x4 pb;
#pragma unroll
        for (int v = 0; v < 4; ++v) pb[v] = (bf16_t)valsH[nt * 4 + v];
        *reinterpret_cast<bf16x4*>(&Pl[wave][1][r * 68 + nt * 16 + kg * 4]) = pb;
      }
      bf16x8 pa0 = *reinterpret_cast<const bf16x8*>(&Pl[wave][1][r * 68 + kg * 8]);
      bf16x8 pa1 = *reinterpret_cast<const bf16x8*>(&Pl[wave][1][r * 68 + 32 + kg * 8]);
      __builtin_amdgcn_s_setprio(1);
#pragma unroll
      for (int dt = 0; dt < 4; ++dt) {
        bf16x8 vb0 = *reinterpret_cast<const bf16x8*>(&Vts[buf][(dt * 16 + r) * 72 + kg * 8]);
        bf16x8 vb1 = *reinterpret_cast<const bf16x8*>(&Vts[buf][(dt * 16 + r) * 72 + 32 + kg * 8]);
        oaccH[dt] = MM(pa0, vb0, oaccH[dt]);
        oaccH[dt] = MM(pa1, vb1, oaccH[dt]);
      }
      __builtin_amdgcn_s_setprio(0);
    }
  }

  // --- epilogue ---
  {
    float l_row = lL;
    l_row += __shfl_xor(l_row, 16);
    l_row += __shfl_xor(l_row, 32);
    const float linv = 1.0f / l_row;
    f32x4 il;
#pragma unroll
    for (int v = 0; v < 4; ++v) il[v] = __shfl(linv, kg * 4 + v);
    const size_t orow0 = o_row0 + (size_t)(q0L + wave * 16) * ostride + ocol;
#pragma unroll
    for (int dt = 0; dt < 4; ++dt) {
      const int d = dt * 16 + r;
#pragma unroll
      for (int v = 0; v < 4; ++v)
        O[orow0 + (size_t)(kg * 4 + v) * ostride + d] = f2b_rne(oaccL[dt][v] * il[v]);
    }
  }
  {
    float l_row = lH;
    l_row += __shfl_xor(l_row, 16);
    l_row += __shfl_xor(l_row, 32);
    const float linv = 1.0f / l_row;
    f32x4 il;
#pragma unroll
    for (int v = 0; v < 4; ++v) il[v] = __shfl(linv, kg * 4 + v);
    const size_t orow0 = o_row0 + (size_t)(q0H + wave * 16) * ostride + ocol;
#pragma unroll
    for (int dt = 0; dt < 4; ++dt) {
      const int d = dt * 16 + r;
#pragma unroll
      for (int v = 0; v < 4; ++v)
        O[orow0 + (size_t)(kg * 4 + v) * ostride + d] = f2b_rne(oaccH[dt][v] * il[v]);
    }
  }
}

// ---------------- launcher ----------------
extern "C" void kernel_launch(void* const* d_in, const int* in_sizes, int n_in,
                              void* d_out, int out_size, void* d_ws, size_t ws_size,
                              hipStream_t stream) {
  const float* x  = (const float*)d_in[0];
  const float* Wq = (const float*)d_in[1];
  const float* Wk = (const float*)d_in[2];
  const float* Wv = (const float*)d_in[3];
  const float* Wo = (const float*)d_in[4];

  char* ws = (char*)d_ws;
  bf16_t* xb  = (bf16_t*)(ws);
  bf16_t* wqb = (bf16_t*)(ws + (16u << 20));
  bf16_t* wob = (bf16_t*)(ws + (22u << 20));
  bf16_t* qkv = (bf16_t*)(ws + (24u << 20));
  bf16_t* vt  = (bf16_t*)(ws);

  hipFuncSetAttribute(reinterpret_cast<const void*>(&gemmk<0, 4>),
                      hipFuncAttributeMaxDynamicSharedMemorySize, 73728);
  hipFuncSetAttribute(reinterpret_cast<const void*>(&gemmk<1, 2>),
                      hipFuncAttributeMaxDynamicSharedMemorySize, 49152);

  // all casts in one launch: 4096 x-blocks + 4*512 weight-blocks
  cast_all<<<4096 + 2048, 256, 0, stream>>>(x, Wq, Wk, Wv, Wo,
                                            (unsigned short*)xb, (unsigned short*)wqb);

  // fused QKV projection; Q cols scaled by 1/sqrt(dk)*log2(e) (exp2-domain softmax)
  gemmk<0, 4><<<dim3(3072 / 256, 8192 / 128), 512, 73728, stream>>>(
      xb, wqb, qkv, 8192, 3072, 1024, 1024, 0.18033688011112042f, 1024);

  transpose_v<<<dim3(2048 / 64, 64), 256, 0, stream>>>(qkv, vt);

  flash_attn<<<dim3(64, 8), 512, 0, stream>>>(qkv, vt, (unsigned short*)qkv, 3072);

  gemmk<1, 2><<<dim3(1024 / 128, 8192 / 128), 512, 49152, stream>>>(
      qkv, wob, d_out, 8192, 1024, 1024, 3072, 1.0f, 0);
}